// Round 8
// baseline (348.361 us; speedup 1.0000x reference)
//
#include <hip/hip_runtime.h>
#include <hip/hip_bf16.h>
#include <math.h>

#define DEV __device__ __forceinline__

typedef short short8 __attribute__((ext_vector_type(8)));
typedef float f32x4  __attribute__((ext_vector_type(4)));

DEV float sigf(float x)   { return 1.0f / (1.0f + __expf(-x)); }
DEV float tanhft(float x) { return 1.0f - 2.0f / (__expf(2.0f * x) + 1.0f); }

DEV unsigned short f2bf(float f) {
    unsigned int u = __float_as_uint(f);
    unsigned int r = (u + 0x7FFFu + ((u >> 16) & 1u)) >> 16;
    return (unsigned short)r;
}
DEV float bf2f(unsigned short u) {
    return __uint_as_float(((unsigned int)u) << 16);
}

// LDS-only barrier: drain LDS ops but leave global loads (vmcnt) in flight.
DEV void bar_lds() {
    asm volatile("s_waitcnt lgkmcnt(0)" ::: "memory");
    __builtin_amdgcn_s_barrier();
}

// ---------------------------------------------------------------------------
// prep: recurrent weights -> bf16 (natural [col][128] layout), bias sums.
// (R6-verified verbatim)
// ---------------------------------------------------------------------------
__global__ __launch_bounds__(256) void prep_kernel(
    const float* __restrict__ w_hh0, const float* __restrict__ w_ih1,
    const float* __restrict__ w_hh1,
    const float* __restrict__ b_ih0, const float* __restrict__ b_hh0,
    const float* __restrict__ b_ih1, const float* __restrict__ b_hh1,
    unsigned short* __restrict__ whh0h, unsigned short* __restrict__ wih1h,
    unsigned short* __restrict__ whh1h,
    float* __restrict__ bias0, float* __restrict__ bias1)
{
    int i = blockIdx.x * 256 + threadIdx.x;
    if (i < 65536) {
        whh0h[i] = f2bf(w_hh0[i]);
        wih1h[i] = f2bf(w_ih1[i]);
        whh1h[i] = f2bf(w_hh1[i]);
    } else if (i < 66048) {
        int c = i - 65536;
        bias0[c] = b_ih0[c] + b_hh0[c];
        bias1[c] = b_ih1[c] + b_hh1[c];
    }
}

// prep iw1 -> bf16 [256][2528], zero-padded K 2500..2527 (R6-verified)
__global__ __launch_bounds__(256) void prep_iw1_kernel(
    const float* __restrict__ iw1, unsigned short* __restrict__ iw1b)
{
    int i = blockIdx.x * 256 + threadIdx.x;
    if (i < 256 * 2528) {
        int row = i / 2528, k = i - row * 2528;
        iw1b[i] = (k < 2500) ? f2bf(iw1[row * 2500 + k]) : (unsigned short)0;
    }
}

// ---------------------------------------------------------------------------
// MFMA LSTM: 256 blocks x 512 threads, 4 batch rows/block, both layers,
// 60 steps. mfma_f32_16x16x32_bf16 (R5/R6-verified dataflow), M=16 with
// rows 4..15 structurally zero.
// R8 delta vs R6 (everything else identical):
//  (a) zero-row skip: lanes l15>=4 feed a ZERO A-frag constant instead of
//      reading LDS zeros — PROVABLY the same A operands as R6 (lanes l15<4
//      read identical addresses); h buffers shrink to 4 rows.
//  (b) whh0/wih1 fragments loaded via VOLATILE 16B loads: a volatile load
//      must execute exactly once, so the compiler cannot rematerialize the
//      fragments by re-loading from L2 each step -> true VGPR residency.
// whh1 still streamed from L2 each step, prefetched across lgkm barriers.
// ---------------------------------------------------------------------------
__global__ __launch_bounds__(512, 2) void lstm_kernel(
    const float* __restrict__ x,
    const unsigned short* __restrict__ whh0,
    const unsigned short* __restrict__ wih1,
    const unsigned short* __restrict__ whh1,
    const float* __restrict__ wih0,
    const float* __restrict__ bias0, const float* __restrict__ bias1,
    float* __restrict__ h2out)
{
    __shared__ __align__(16) float          xs[4][304];
    __shared__ __align__(16) unsigned short h0s[2][4][136];
    __shared__ __align__(16) unsigned short h1s[2][4][136];
    __shared__ float gbuf0[4][512];
    __shared__ float gbuf1[4][512];
    __shared__ float wih0s[2560];

    const int tid = threadIdx.x;
    const int b0  = blockIdx.x * 4;
    const int l15 = tid & 15;          // MFMA A-row / C-col lane index
    const int q   = (tid >> 4) & 3;    // lane quad
    const int w   = tid >> 6;          // wave 0..7
    const int j   = w * 16 + l15;      // gate column owned in C/D
    const int q8  = q * 8;
    const int r_u = tid >> 7;          // update role: row 0..3
    const int j_u = tid & 127;         // update role: hidden unit

    for (int i = tid; i < 1200; i += 512) {
        int m = i / 300, kk = i - m * 300;
        xs[m][kk] = x[(b0 + m) * 300 + kk];
    }
    for (int i = tid; i < 2560; i += 512) wih0s[i] = wih0[i];
    for (int i = tid; i < 544; i += 512) {
        ((unsigned int*)h0s)[i] = 0u;
        ((unsigned int*)h1s)[i] = 0u;
    }

    const float ub0[4] = {bias0[j_u], bias0[128 + j_u], bias0[256 + j_u], bias0[384 + j_u]};
    const float ub1[4] = {bias1[j_u], bias1[128 + j_u], bias1[256 + j_u], bias1[384 + j_u]};

    // ---- resident B-fragments: w_hh0, w_ih1 — volatile loads (exactly-once
    //      semantics forbids re-load; forces VGPR residency)
    short8 bh0[4][4], b1i[4][4];
    {
        const volatile short8* w0v = (const volatile short8*)whh0;
        const volatile short8* w1v = (const volatile short8*)wih1;
#pragma unroll
        for (int g = 0; g < 4; ++g)
#pragma unroll
            for (int kc = 0; kc < 4; ++kc) {
                int so = (g * 128 + j) * 16 + kc * 4 + q;
                bh0[g][kc] = w0v[so];
                b1i[g][kc] = w1v[so];
            }
    }

    float c0 = 0.f, c1 = 0.f, hl = 0.f;
    const short8 zf = (short8){0, 0, 0, 0, 0, 0, 0, 0};
    __syncthreads();

    const unsigned short* wsb = whh1 + j * 128 + q8;  // per-lane stream base

    for (int t = 0; t < 60; ++t) {
        const int p = t & 1;

        // ---- prefetch streamed w_hh1, first half
        short8 wsv[4][4];
#pragma unroll
        for (int g = 0; g < 4; ++g) {
            wsv[g][0] = *(const short8*)(wsb + g * 16384);
            wsv[g][1] = *(const short8*)(wsb + g * 16384 + 32);
        }

        // ---- layer 0 MFMA: h0[p] @ w_hh0^T
        f32x4 acc[4];
#pragma unroll
        for (int g = 0; g < 4; ++g) acc[g] = (f32x4){0.f, 0.f, 0.f, 0.f};
        short8 af[4];
        if (l15 < 4) {
#pragma unroll
            for (int kc = 0; kc < 4; ++kc)
                af[kc] = *(const short8*)&h0s[p][l15][kc * 32 + q8];
        } else {
#pragma unroll
            for (int kc = 0; kc < 4; ++kc) af[kc] = zf;
        }
#pragma unroll
        for (int kc = 0; kc < 4; ++kc)
#pragma unroll
            for (int g = 0; g < 4; ++g)
                acc[g] = __builtin_amdgcn_mfma_f32_16x16x32_bf16(af[kc], bh0[g][kc], acc[g], 0, 0, 0);

        // ---- prefetch streamed w_hh1, second half
#pragma unroll
        for (int g = 0; g < 4; ++g) {
            wsv[g][2] = *(const short8*)(wsb + g * 16384 + 64);
            wsv[g][3] = *(const short8*)(wsb + g * 16384 + 96);
        }

        if (q == 0) {
#pragma unroll
            for (int g = 0; g < 4; ++g)
#pragma unroll
                for (int r = 0; r < 4; ++r)
                    gbuf0[r][g * 128 + j] = acc[g][r];
        }
        bar_lds();  // BAR1

        // ---- layer 0 update: 1 element/thread (row r_u, unit j_u)
        {
            const float* xr = &xs[r_u][t * 5];
            float x0 = xr[0], x1 = xr[1], x2 = xr[2], x3 = xr[3], x4 = xr[4];
            float gv[4];
#pragma unroll
            for (int g = 0; g < 4; ++g) {
                const float* wr = &wih0s[(g * 128 + j_u) * 5];
                float s = gbuf0[r_u][g * 128 + j_u] + ub0[g];
                s = fmaf(x0, wr[0], s);
                s = fmaf(x1, wr[1], s);
                s = fmaf(x2, wr[2], s);
                s = fmaf(x3, wr[3], s);
                gv[g] = fmaf(x4, wr[4], s);
            }
            c0 = sigf(gv[1]) * c0 + sigf(gv[0]) * tanhft(gv[2]);
            float h = sigf(gv[3]) * tanhft(c0);
            h0s[1 - p][r_u][j_u] = f2bf(h);
        }
        bar_lds();  // BAR2

        // ---- layer 1 MFMA: h0new @ w_ih1^T + h1[p] @ w_hh1^T
#pragma unroll
        for (int g = 0; g < 4; ++g) acc[g] = (f32x4){0.f, 0.f, 0.f, 0.f};
        if (l15 < 4) {
#pragma unroll
            for (int kc = 0; kc < 4; ++kc)
                af[kc] = *(const short8*)&h0s[1 - p][l15][kc * 32 + q8];
        } else {
#pragma unroll
            for (int kc = 0; kc < 4; ++kc) af[kc] = zf;
        }
#pragma unroll
        for (int kc = 0; kc < 4; ++kc)
#pragma unroll
            for (int g = 0; g < 4; ++g)
                acc[g] = __builtin_amdgcn_mfma_f32_16x16x32_bf16(af[kc], b1i[g][kc], acc[g], 0, 0, 0);
        if (l15 < 4) {
#pragma unroll
            for (int kc = 0; kc < 4; ++kc)
                af[kc] = *(const short8*)&h1s[p][l15][kc * 32 + q8];
        } else {
#pragma unroll
            for (int kc = 0; kc < 4; ++kc) af[kc] = zf;
        }
#pragma unroll
        for (int kc = 0; kc < 4; ++kc)
#pragma unroll
            for (int g = 0; g < 4; ++g)
                acc[g] = __builtin_amdgcn_mfma_f32_16x16x32_bf16(af[kc], wsv[g][kc], acc[g], 0, 0, 0);

        if (q == 0) {
#pragma unroll
            for (int g = 0; g < 4; ++g)
#pragma unroll
                for (int r = 0; r < 4; ++r)
                    gbuf1[r][g * 128 + j] = acc[g][r];
        }
        bar_lds();  // BAR3

        // ---- layer 1 update
        {
            float gv[4];
#pragma unroll
            for (int g = 0; g < 4; ++g)
                gv[g] = gbuf1[r_u][g * 128 + j_u] + ub1[g];
            c1 = sigf(gv[1]) * c1 + sigf(gv[0]) * tanhft(gv[2]);
            float h = sigf(gv[3]) * tanhft(c1);
            h1s[1 - p][r_u][j_u] = f2bf(h);
            hl = h;
        }
        // next-iter BAR1 orders the remaining hazards
    }

    h2out[(b0 + r_u) * 128 + j_u] = hl;
}

// ---------------------------------------------------------------------------
// base = tanh(relu(h2 @ pw1^T + pb1) @ pw2^T + pb2)  — R6-verified verbatim.
// ---------------------------------------------------------------------------
__global__ __launch_bounds__(64) void phase2_kernel(
    const float* __restrict__ h2, const float* __restrict__ pw1,
    const float* __restrict__ pb1, const float* __restrict__ pw2,
    const float* __restrict__ pb2, float* __restrict__ base)
{
    __shared__ float hs[128], p1[64];
    int b = blockIdx.x, tid = threadIdx.x;
    hs[tid] = h2[b * 128 + tid];
    hs[tid + 64] = h2[b * 128 + 64 + tid];
    __syncthreads();
    float acc = pb1[tid];
#pragma unroll 4
    for (int k = 0; k < 128; ++k) acc = fmaf(hs[k], pw1[tid * 128 + k], acc);
    p1[tid] = fmaxf(acc, 0.f);
    __syncthreads();
    if (tid < 32) {
        float a2 = pb2[tid];
#pragma unroll 4
        for (int k = 0; k < 64; ++k) a2 = fmaf(p1[k], pw2[tid * 64 + k], a2);
        base[b * 32 + tid] = tanhft(a2);
    }
}

// ---------------------------------------------------------------------------
// W_eff^T[j][n] = sum_{k: conn_idx[n,k]%32==j} conn_w[n,k]  (R6-verified)
// ---------------------------------------------------------------------------
__global__ __launch_bounds__(128) void weff_kernel(
    const int* __restrict__ conn_idx, const float* __restrict__ conn_w,
    float* __restrict__ weffT)
{
    __shared__ float s[128 * 33];
    int tid = threadIdx.x;
    int n = blockIdx.x * 128 + tid;
    float* sr = &s[tid * 33];
#pragma unroll
    for (int j = 0; j < 32; ++j) sr[j] = 0.f;
    if (n < 2500) {
        for (int k = 0; k < 50; ++k) {
            int idx = conn_idx[n * 50 + k];
            sr[idx & 31] += conn_w[n * 50 + k];
        }
        for (int j = 0; j < 32; ++j) weffT[j * 2500 + n] = sr[j];
    }
}

// ---------------------------------------------------------------------------
// z = (base @ W_eff^T)*sens; a = per-group activation; amat bf16 [b][2528].
// (R6-verified verbatim)
// ---------------------------------------------------------------------------
__global__ __launch_bounds__(256) void za_kernel(
    const float* __restrict__ base, const float* __restrict__ weffT,
    const float* __restrict__ sens, const float* __restrict__ thr,
    unsigned short* __restrict__ amat)
{
    __shared__ float bs[16][32];
    int tid = threadIdx.x;
    int bb = blockIdx.x / 10, nb = blockIdx.x % 10;
    int n = nb * 256 + tid;
    bool nv = n < 2500;
    bool pv = n < 2528;
    int nn = nv ? n : 0;
    for (int i = tid; i < 512; i += 256) bs[i >> 5][i & 31] = base[bb * 512 + i];
    __syncthreads();
    float w[32];
#pragma unroll
    for (int j = 0; j < 32; ++j) w[j] = weffT[j * 2500 + nn];
    float sn = sens[nn], tn = thr[nn];
    int g = (n < 800) ? 0 : (n < 1500) ? 1 : (n < 2100) ? 2 : 3;
#pragma unroll 2
    for (int r = 0; r < 16; ++r) {
        float z = 0.f;
#pragma unroll
        for (int j = 0; j < 32; ++j) z = fmaf(bs[r][j], w[j], z);
        z *= sn;
        float av;
        if (g == 0)      av = sigf(z - tn);
        else if (g == 1) av = tanhft(z);
        else if (g == 2) av = fmaxf(z - tn, 0.f);
        else             av = sigf(z);
        if (nv)      amat[(bb * 16 + r) * 2528 + n] = f2bf(av);
        else if (pv) amat[(bb * 16 + r) * 2528 + n] = 0;
    }
}

// ---------------------------------------------------------------------------
// t1 = relu(a @ iw1^T + ib1): M=1024 N=256 K=2528, bf16 MFMA register
// streaming (R6-verified verbatim: grid (4,32), 4 col-tiles/wave).
// ---------------------------------------------------------------------------
__global__ __launch_bounds__(128) void gemm_iw1_kernel(
    const unsigned short* __restrict__ ab, const unsigned short* __restrict__ wb,
    const float* __restrict__ ib1, float* __restrict__ t1)
{
    const int tid = threadIdx.x;
    const int wv  = tid >> 6;
    const int l15 = tid & 15, q = (tid >> 4) & 3, q8 = q * 8;
    const int row0 = blockIdx.y * 32 + wv * 16;
    const int col0 = blockIdx.x * 64;

    const unsigned short* A = ab + (row0 + l15) * 2528 + q8;
    const unsigned short* B = wb + (col0 + l15) * 2528 + q8;

    short8 a = *(const short8*)A;
    short8 b[4];
#pragma unroll
    for (int nt = 0; nt < 4; ++nt) b[nt] = *(const short8*)(B + nt * 16 * 2528);

    f32x4 acc[4];
#pragma unroll
    for (int nt = 0; nt < 4; ++nt) acc[nt] = (f32x4){0.f, 0.f, 0.f, 0.f};

    for (int c = 0; c < 79; ++c) {
        int cn = (c < 78) ? c + 1 : 78;
        short8 an = *(const short8*)(A + cn * 32);
        short8 bn[4];
#pragma unroll
        for (int nt = 0; nt < 4; ++nt)
            bn[nt] = *(const short8*)(B + nt * 16 * 2528 + cn * 32);
#pragma unroll
        for (int nt = 0; nt < 4; ++nt)
            acc[nt] = __builtin_amdgcn_mfma_f32_16x16x32_bf16(a, b[nt], acc[nt], 0, 0, 0);
        a = an;
#pragma unroll
        for (int nt = 0; nt < 4; ++nt) b[nt] = bn[nt];
    }

#pragma unroll
    for (int nt = 0; nt < 4; ++nt) {
        int n = col0 + nt * 16 + l15;
        float bias = ib1[n];
#pragma unroll
        for (int i = 0; i < 4; ++i) {
            int row = row0 + q * 4 + i;
            t1[row * 256 + n] = fmaxf(acc[nt][i] + bias, 0.f);
        }
    }
}

// ---------------------------------------------------------------------------
// t2 = relu(t1@iw2^T+ib2); integ = tanh(t2@iw3^T+ib3); heads — R6-verified.
// ---------------------------------------------------------------------------
__global__ __launch_bounds__(64) void final_kernel(
    const float* __restrict__ t1, const float* __restrict__ iw2,
    const float* __restrict__ ib2, const float* __restrict__ iw3,
    const float* __restrict__ ib3,
    const float* __restrict__ hw_trend, const float* __restrict__ hb_trend,
    const float* __restrict__ hw_pat,   const float* __restrict__ hb_pat,
    const float* __restrict__ hw_key,   const float* __restrict__ hb_key,
    const float* __restrict__ hw_vol,   const float* __restrict__ hb_vol,
    const float* __restrict__ hw_conf,  const float* __restrict__ hb_conf,
    float* __restrict__ out)
{
    __shared__ float t1s[256], t2s[64], igs[32];
    int b = blockIdx.x, tid = threadIdx.x;
#pragma unroll
    for (int i = 0; i < 4; ++i) t1s[tid + i * 64] = t1[b * 256 + tid + i * 64];
    __syncthreads();
    float acc = ib2[tid];
#pragma unroll 4
    for (int k = 0; k < 256; ++k) acc = fmaf(t1s[k], iw2[tid * 256 + k], acc);
    t2s[tid] = fmaxf(acc, 0.f);
    __syncthreads();
    if (tid < 32) {
        float a2 = ib3[tid];
#pragma unroll 4
        for (int k = 0; k < 64; ++k) a2 = fmaf(t2s[k], iw3[tid * 64 + k], a2);
        igs[tid] = tanhft(a2);
    }
    __syncthreads();
    if (tid < 15) {
        const float* w; const float* bb; int j, off;
        if (tid < 3)        { w = hw_trend; bb = hb_trend; j = tid;     off = 0; }
        else if (tid < 9)   { w = hw_pat;   bb = hb_pat;   j = tid - 3; off = 3; }
        else if (tid < 13)  { w = hw_key;   bb = hb_key;   j = tid - 9; off = 9; }
        else if (tid == 13) { w = hw_vol;   bb = hb_vol;   j = 0;       off = 13; }
        else                { w = hw_conf;  bb = hb_conf;  j = 0;       off = 14; }
        float a3 = bb[j];
#pragma unroll
        for (int k = 0; k < 32; ++k) a3 = fmaf(igs[k], w[j * 32 + k], a3);
        out[b * 20 + off + j] = a3;
        if (tid == 14) out[b * 20 + 15] = sigf(a3);
    }
}

// ---------------------------------------------------------------------------
// group means of a (bf16, pitch 2528) -> out[:, 16:20]  (R6-verified)
// ---------------------------------------------------------------------------
__global__ __launch_bounds__(256) void means_kernel(
    const unsigned short* __restrict__ amat, float* __restrict__ out)
{
    __shared__ float red[256];
    int b = blockIdx.x, tid = threadIdx.x;
    float parts[4] = {0.f, 0.f, 0.f, 0.f};
    for (int n = tid; n < 2500; n += 256) {
        float v = bf2f(amat[b * 2528 + n]);
        if (n < 800)       parts[0] += v;
        else if (n < 1500) parts[1] += v;
        else if (n < 2100) parts[2] += v;
        else               parts[3] += v;
    }
    const float inv[4] = {1.f / 800.f, 1.f / 700.f, 1.f / 600.f, 1.f / 400.f};
#pragma unroll
    for (int g = 0; g < 4; ++g) {
        red[tid] = parts[g];
        __syncthreads();
        for (int s = 128; s > 0; s >>= 1) {
            if (tid < s) red[tid] += red[tid + s];
            __syncthreads();
        }
        if (tid == 0) out[b * 20 + 16 + g] = red[0] * inv[g];
        __syncthreads();
    }
}

// ---------------------------------------------------------------------------
extern "C" void kernel_launch(void* const* d_in, const int* in_sizes, int n_in,
                              void* d_out, int out_size, void* d_ws, size_t ws_size,
                              hipStream_t stream)
{
    const float* x        = (const float*)d_in[0];
    const int*   conn_idx = (const int*)  d_in[1];
    const float* w_ih0    = (const float*)d_in[2];
    const float* w_hh0    = (const float*)d_in[3];
    const float* b_ih0    = (const float*)d_in[4];
    const float* b_hh0    = (const float*)d_in[5];
    const float* w_ih1    = (const float*)d_in[6];
    const float* w_hh1    = (const float*)d_in[7];
    const float* b_ih1    = (const float*)d_in[8];
    const float* b_hh1    = (const float*)d_in[9];
    const float* pw1      = (const float*)d_in[10];
    const float* pb1      = (const float*)d_in[11];
    const float* pw2      = (const float*)d_in[12];
    const float* pb2      = (const float*)d_in[13];
    const float* conn_w   = (const float*)d_in[14];
    const float* sens     = (const float*)d_in[15];
    const float* thr      = (const float*)d_in[16];
    const float* iw1      = (const float*)d_in[17];
    const float* ib1      = (const float*)d_in[18];
    const float* iw2      = (const float*)d_in[19];
    const float* ib2      = (const float*)d_in[20];
    const float* iw3      = (const float*)d_in[21];
    const float* ib3      = (const float*)d_in[22];
    const float* hw_trend = (const float*)d_in[23];
    const float* hb_trend = (const float*)d_in[24];
    const float* hw_pat   = (const float*)d_in[25];
    const float* hb_pat   = (const float*)d_in[26];
    const float* hw_key   = (const float*)d_in[27];
    const float* hb_key   = (const float*)d_in[28];
    const float* hw_vol   = (const float*)d_in[29];
    const float* hb_vol   = (const float*)d_in[30];
    const float* hw_conf  = (const float*)d_in[31];
    const float* hb_conf  = (const float*)d_in[32];
    float* out = (float*)d_out;
    float* ws  = (float*)d_ws;

    unsigned short* whh0h = (unsigned short*)(ws);           // 32768 f
    unsigned short* wih1h = (unsigned short*)(ws + 32768);   // 32768 f
    unsigned short* whh1h = (unsigned short*)(ws + 65536);   // 32768 f
    float* bias0  = ws + 98304;   // 512
    float* bias1  = ws + 98816;   // 512
    float* h2     = ws + 99328;   // 131072
    float* base_  = ws + 230400;  // 32768
    float* weffT  = ws + 263168;  // 80000
    float* t1     = ws + 343168;  // 262144
    unsigned short* iw1b   = (unsigned short*)(ws + 605312); // 323584 f
    unsigned short* amatbf = (unsigned short*)(ws + 928896); // 1294336 f

    prep_kernel<<<258, 256, 0, stream>>>(w_hh0, w_ih1, w_hh1,
                                         b_ih0, b_hh0, b_ih1, b_hh1,
                                         whh0h, wih1h, whh1h, bias0, bias1);
    prep_iw1_kernel<<<2528, 256, 0, stream>>>(iw1, iw1b);
    lstm_kernel<<<256, 512, 0, stream>>>(x, whh0h, wih1h, whh1h, w_ih0,
                                         bias0, bias1, h2);
    phase2_kernel<<<1024, 64, 0, stream>>>(h2, pw1, pb1, pw2, pb2, base_);
    weff_kernel<<<20, 128, 0, stream>>>(conn_idx, conn_w, weffT);
    za_kernel<<<640, 256, 0, stream>>>(base_, weffT, sens, thr, amatbf);
    gemm_iw1_kernel<<<dim3(4, 32), 128, 0, stream>>>(amatbf, iw1b, ib1, t1);
    final_kernel<<<1024, 64, 0, stream>>>(t1, iw2, ib2, iw3, ib3,
                                          hw_trend, hb_trend, hw_pat, hb_pat,
                                          hw_key, hb_key, hw_vol, hb_vol,
                                          hw_conf, hb_conf, out);
    means_kernel<<<1024, 256, 0, stream>>>(amatbf, out);
}